// Round 1
// baseline (317.311 us; speedup 1.0000x reference)
//
#include <hip/hip_runtime.h>
#include <stdint.h>

#define NUM_EXPERT 8
#define IN_FEAT 1024
#define OUT_FEAT 4096
#define N_TOKENS 4096

#define BM 128
#define BN 128
#define BK 64
#define MAX_ROW_TILES 40      // worst-case sum_e ceil(cnt_e/128) = 32+7 <= 40

typedef __attribute__((ext_vector_type(8))) short short8;   // 8 x bf16 bits
typedef __attribute__((ext_vector_type(4))) float f32x4;

__device__ __forceinline__ unsigned int rne2(float a, float b) {
    // pack 2 fp32 -> 2 bf16 (RNE) into one dword (a=low, b=high)
    unsigned int ua = __float_as_uint(a); ua += 0x7fffu + ((ua >> 16) & 1u);
    unsigned int ub = __float_as_uint(b); ub += 0x7fffu + ((ub >> 16) & 1u);
    return (ua >> 16) | (ub & 0xffff0000u);
}

__device__ __forceinline__ uint4 cvt8(float4 v0, float4 v1) {
    // 8 fp32 -> 8 bf16 (16 B), ready for one ds_write_b128
    uint4 r;
    r.x = rne2(v0.x, v0.y);
    r.y = rne2(v0.z, v0.w);
    r.z = rne2(v1.x, v1.y);
    r.w = rne2(v1.z, v1.w);
    return r;
}

// ---------------- Kernel 1: gate sort only (1 block) -------------------------
// meta layout (int): [0..7]=cnt, [8..15]=off, [16..16+4096)=perm
__global__ __launch_bounds__(256)
void moe_sort(const int* __restrict__ gate, int* __restrict__ meta) {
    __shared__ int cnt[NUM_EXPERT];
    __shared__ int off[NUM_EXPERT];
    __shared__ int wsum[4];
    const int tid  = threadIdx.x;
    const int lane = tid & 63;
    const int wave = tid >> 6;

    int gv[16];
    const int4* gp = (const int4*)(gate + tid * 16);
#pragma unroll
    for (int i = 0; i < 4; ++i) {
        int4 v = gp[i];
        gv[i * 4 + 0] = v.x; gv[i * 4 + 1] = v.y;
        gv[i * 4 + 2] = v.z; gv[i * 4 + 3] = v.w;
    }
    int lc[NUM_EXPERT];
#pragma unroll
    for (int e = 0; e < NUM_EXPERT; ++e) {
        int c = 0;
#pragma unroll
        for (int j = 0; j < 16; ++j) c += (gv[j] == e) ? 1 : 0;
        lc[e] = c;
    }
    if (tid < NUM_EXPERT) cnt[tid] = 0;
    __syncthreads();
#pragma unroll
    for (int e = 0; e < NUM_EXPERT; ++e) {
        int c = lc[e];
#pragma unroll
        for (int d = 32; d > 0; d >>= 1) c += __shfl_down(c, d);
        if (lane == 0 && c) atomicAdd(&cnt[e], c);
    }
    __syncthreads();
    if (tid == 0) {
        int a = 0;
#pragma unroll
        for (int e = 0; e < NUM_EXPERT; ++e) { off[e] = a; a += cnt[e]; }
    }
    __syncthreads();
    if (tid < NUM_EXPERT) { meta[tid] = cnt[tid]; meta[8 + tid] = off[tid]; }

    int* perm = meta + 16;
#pragma unroll
    for (int e = 0; e < NUM_EXPERT; ++e) {
        int c_t = lc[e];
        int inc = c_t;
#pragma unroll
        for (int d = 1; d < 64; d <<= 1) {
            int t = __shfl_up(inc, d);
            if (lane >= d) inc += t;
        }
        if (lane == 63) wsum[wave] = inc;
        __syncthreads();
        int base = off[e];
#pragma unroll
        for (int w = 0; w < 4; ++w) if (w < wave) base += wsum[w];
        int rank = base + inc - c_t;
#pragma unroll
        for (int j = 0; j < 16; ++j) {
            if (gv[j] == e) { perm[rank] = tid * 16 + j; rank++; }
        }
        __syncthreads();
    }
}

// ---------------- Kernel 2: fused fp32->bf16 grouped GEMM --------------------
// C[tok][n] = sum_k inp[tok][k] * W[e][n][k]
// Reads fp32 operands directly; converts to bf16 in registers during LDS
// staging (reg-staged ds_write_b128, XOR-swizzled — same fragment-read layout
// as the previous global_load_lds version). Eliminates the 216 MB HBM
// round-trip of the old conversion pass.
__global__ __launch_bounds__(256)
void moe_gemm_fused(const float* __restrict__ inp,
                    const float* __restrict__ weight,
                    const int* __restrict__ meta,
                    float* __restrict__ out) {
    __shared__ __align__(16) unsigned short As[BM * BK];   // 16 KB
    __shared__ __align__(16) unsigned short Bs[BN * BK];   // 16 KB (total 32768 B)

    const int* cnt  = meta;
    const int* off  = meta + 8;
    const int* perm = meta + 16;

    // ---- map blockIdx.y -> (expert, local row-tile); block-uniform ----
    int local = blockIdx.y;
    int e = -1, grp_cnt = 0, grp_off = 0;
#pragma unroll
    for (int i = 0; i < NUM_EXPERT; ++i) {
        int c = cnt[i];
        int t = (c + BM - 1) >> 7;
        if (e < 0) {
            if (local < t) { e = i; grp_cnt = c; grp_off = off[i]; }
            else           local -= t;
        }
    }
    if (e < 0) return;

    const int n0   = blockIdx.x * BN;
    const int row0 = local * BM;
    int vcnt = grp_cnt - row0; if (vcnt > BM) vcnt = BM;

    const int tid  = threadIdx.x;
    const int lane = tid & 63;
    const int wave = tid >> 6;

    // ---- staging descriptors: thread stages chunks c = i*256+tid.
    // LDS slot (row=c>>3, kcp=c&7) receives global k-chunk kc = kcp ^ (row&7);
    // one chunk = 8 k-elems = 32 B fp32 in global = 16 B bf16 in LDS.
    const char* ag[4]; const char* bg[4];
    char* al[4]; char* bl[4];
    const char* inp_b = (const char*)inp;
    const char* w_b   = (const char*)weight + (size_t)e * (size_t)(OUT_FEAT * IN_FEAT) * 4;
#pragma unroll
    for (int i = 0; i < 4; ++i) {
        int c   = i * 256 + tid;
        int row = c >> 3;
        int kc  = (c & 7) ^ (row & 7);
        int p   = row0 + row; if (p > grp_cnt - 1) p = grp_cnt - 1;  // clamp tail
        int tok = perm[grp_off + p];
        ag[i] = inp_b + (size_t)tok * (IN_FEAT * 4) + kc * 32;
        bg[i] = w_b   + (size_t)(n0 + row) * (IN_FEAT * 4) + kc * 32;
        al[i] = (char*)As + c * 16;
        bl[i] = (char*)Bs + c * 16;
    }

    // ---- fragment LDS byte offsets: row*128 + ((ks*4+quad)^(row&7))*16 ----
    const int wm   = (wave & 1) * 64;
    const int wn   = (wave >> 1) * 64;
    const int lcol = lane & 15;
    const int quad = lane >> 4;

    int aoff[2][4], boff[2][4];
#pragma unroll
    for (int ks = 0; ks < 2; ++ks)
#pragma unroll
        for (int t = 0; t < 4; ++t) {
            int ra = wm + t * 16 + lcol;
            aoff[ks][t] = ra * 128 + (((ks * 4 + quad) ^ (ra & 7)) * 16);
            int rb = wn + t * 16 + lcol;
            boff[ks][t] = rb * 128 + (((ks * 4 + quad) ^ (rb & 7)) * 16);
        }

    const f32x4 vzero = {0.f, 0.f, 0.f, 0.f};
    f32x4 acc[4][4];
#pragma unroll
    for (int i = 0; i < 4; ++i)
#pragma unroll
        for (int j = 0; j < 4; ++j) acc[i][j] = vzero;

    const char* As_b = (const char*)As;
    const char* Bs_b = (const char*)Bs;

    for (int k0 = 0; k0 < IN_FEAT; k0 += BK) {
        // ---- stage: fp32 load -> bf16 cvt in regs -> swizzled ds_write ----
#pragma unroll
        for (int i = 0; i < 4; ++i) {
            float4 v0 = *(const float4*)(ag[i]);
            float4 v1 = *(const float4*)(ag[i] + 16);
            ag[i] += BK * 4;
            *(uint4*)al[i] = cvt8(v0, v1);
        }
#pragma unroll
        for (int i = 0; i < 4; ++i) {
            float4 v0 = *(const float4*)(bg[i]);
            float4 v1 = *(const float4*)(bg[i] + 16);
            bg[i] += BK * 4;
            *(uint4*)bl[i] = cvt8(v0, v1);
        }
        __syncthreads();
#pragma unroll
        for (int ks = 0; ks < 2; ++ks) {
            short8 af[4], bf[4];
#pragma unroll
            for (int im = 0; im < 4; ++im) af[im] = *(const short8*)(As_b + aoff[ks][im]);
#pragma unroll
            for (int jn = 0; jn < 4; ++jn) bf[jn] = *(const short8*)(Bs_b + boff[ks][jn]);
#pragma unroll
            for (int im = 0; im < 4; ++im)
#pragma unroll
                for (int jn = 0; jn < 4; ++jn)
                    acc[im][jn] = __builtin_amdgcn_mfma_f32_16x16x32_bf16(
                        af[im], bf[jn], acc[im][jn], 0, 0, 0);
        }
        __syncthreads();
    }

    // ---- epilogue: C/D layout col=lane&15, row=quad*4+reg; fp32 scatter ----
#pragma unroll
    for (int im = 0; im < 4; ++im) {
#pragma unroll
        for (int reg = 0; reg < 4; ++reg) {
            int r = wm + im * 16 + quad * 4 + reg;
            if (r < vcnt) {
                int tok = perm[grp_off + row0 + r];
                float* orow = out + (size_t)tok * OUT_FEAT + (n0 + wn + lcol);
#pragma unroll
                for (int jn = 0; jn < 4; ++jn)
                    orow[jn * 16] = acc[im][jn][reg];
            }
        }
    }
}

extern "C" void kernel_launch(void* const* d_in, const int* in_sizes, int n_in,
                              void* d_out, int out_size, void* d_ws, size_t ws_size,
                              hipStream_t stream) {
    const float* inp    = (const float*)d_in[0];   // fp32 [4096,1024]
    const int*   gate   = (const int*)d_in[1];     // int32 [4096]
    const float* weight = (const float*)d_in[2];   // fp32 [8,4096,1024]
    float*       out    = (float*)d_out;           // fp32 [4096,4096]
    (void)in_sizes; (void)n_in; (void)out_size; (void)ws_size;

    int* meta = (int*)d_ws;    // cnt/off/perm (~16.5 KB) — only ws use now

    moe_sort<<<1, 256, 0, stream>>>(gate, meta);
    dim3 grid(OUT_FEAT / BN, MAX_ROW_TILES);
    moe_gemm_fused<<<grid, 256, 0, stream>>>(inp, weight, meta, out);
}